// Round 1
// baseline (343.132 us; speedup 1.0000x reference)
//
#include <hip/hip_runtime.h>
#include <hip/hip_bf16.h>

#define B_ 32
#define T_ 1024
#define H_ 16
#define D_ 64
#define M_ (B_*T_)      // 32768 rows
#define N_ (H_*D_*2)    // 2048 cols (h,d,k)
#define K_ 1024
#define CHUNKS 16
#define CLEN (T_/CHUNKS)

typedef __bf16 bf16x8 __attribute__((ext_vector_type(8)));
typedef float  f32x4  __attribute__((ext_vector_type(4)));

__device__ __forceinline__ float bf2f(unsigned short u){
  union{ float f; unsigned int i; } c; c.i = ((unsigned int)u) << 16; return c.f;
}
__device__ __forceinline__ unsigned short f2bf(float f){
  union{ float f; unsigned int i; } c; c.f = f;
  unsigned int r = (c.i + 0x7FFFu + ((c.i >> 16) & 1u)) >> 16;   // RNE
  return (unsigned short)r;
}
__device__ __forceinline__ float silu(float x){ return x / (1.0f + __expf(-x)); }

__device__ __forceinline__ void gload16(const void* g, void* l){
  __builtin_amdgcn_global_load_lds(
      (const __attribute__((address_space(1))) void*)g,
      (__attribute__((address_space(3))) void*)l, 16, 0, 0);
}

// ---- K0: x f32 -> bf16 ------------------------------------------------
__global__ __launch_bounds__(256) void cvt_x(const float* __restrict__ x,
                                             unsigned short* __restrict__ xb, int n){
  int i = (blockIdx.x * 256 + threadIdx.x) * 4;
  int stride = gridDim.x * 256 * 4;
  for(; i < n; i += stride){
    float4 v = *(const float4*)(x + i);
    ushort4 o;
    o.x = f2bf(v.x); o.y = f2bf(v.y); o.z = f2bf(v.z); o.w = f2bf(v.w);
    *(ushort4*)(xb + i) = o;
  }
}

// ---- K1: W [K][N] f32 -> Wt [N][K] bf16 (LDS transpose) ---------------
__global__ __launch_bounds__(256) void cvt_w(const float* __restrict__ w,
                                             unsigned short* __restrict__ wt){
  __shared__ unsigned short tile[64][65];
  int kt = blockIdx.x * 64, nt = blockIdx.y * 64;
  int t = threadIdx.x, tn = t & 63, tk4 = t >> 6;
  #pragma unroll
  for(int r = 0; r < 16; ++r){
    int kl = r * 4 + tk4;
    tile[tn][kl] = f2bf(w[(kt + kl) * N_ + nt + tn]);
  }
  __syncthreads();
  #pragma unroll
  for(int r = 0; r < 16; ++r){
    int nl = r * 4 + tk4;
    wt[(nt + nl) * K_ + kt + tn] = tile[nl][tn];
  }
}

// ---- K2: GEMM (bf16 MFMA) + silu + v-store + fused s = q.k ------------
#define BM 128
#define BN 128
#define BK 32
__global__ __launch_bounds__(256) void gemm_fused(
    const unsigned short* __restrict__ xb,   // [M][K]
    const unsigned short* __restrict__ wt,   // [N][K]
    const float*  __restrict__ q,            // [H][D]
    unsigned short* __restrict__ vout,       // [M][H][D]
    float* __restrict__ s)                   // [M][H]
{
  __shared__ __align__(16) unsigned short As[BM*BK];
  __shared__ __align__(16) unsigned short Bs[BN*BK];
  __shared__ float sl[2][128];

  const int brow = blockIdx.x * BM;
  const int h    = blockIdx.y;            // one head per N-tile (128 cols)
  const int bcol = h * BN;
  const int t = threadIdx.x, lane = t & 63, w = t >> 6;
  const int wr = w >> 1, wc = w & 1;

  f32x4 acc[4][4] = {};

  const unsigned short* gA = xb + (brow + (t >> 2)) * K_ + (t & 3) * 8;
  const unsigned short* gB = wt + (bcol + (t >> 2)) * K_ + (t & 3) * 8;
  unsigned short* lA = As + t * 8;   // lane-linear: byte off = tid*16
  unsigned short* lB = Bs + t * 8;

  const int arow = wr * 64 + (lane & 15);
  const int nrow = wc * 64 + (lane & 15);
  const int koff = (lane >> 4) * 8;

  for(int k0 = 0; k0 < K_; k0 += BK){
    gload16(gA + k0,            lA);
    gload16(gA + 64*K_ + k0,    lA + 2048);
    gload16(gB + k0,            lB);
    gload16(gB + 64*K_ + k0,    lB + 2048);
    __syncthreads();                      // drains vmcnt -> LDS tile ready
    bf16x8 a[4], b[4];
    #pragma unroll
    for(int mi = 0; mi < 4; ++mi)
      a[mi] = *(const bf16x8*)(As + (arow + mi*16) * BK + koff);
    #pragma unroll
    for(int ni = 0; ni < 4; ++ni)
      b[ni] = *(const bf16x8*)(Bs + (nrow + ni*16) * BK + koff);
    #pragma unroll
    for(int mi = 0; mi < 4; ++mi)
      #pragma unroll
      for(int ni = 0; ni < 4; ++ni)
        acc[mi][ni] = __builtin_amdgcn_mfma_f32_16x16x32_bf16(a[mi], b[ni], acc[mi][ni], 0, 0, 0);
    __syncthreads();                      // protect LDS before next stage
  }

  // Epilogue. col c = wc*64 + ni*16 + (lane&15); parity = lane&1.
  // odd lane -> v-projection (write), even lane -> k-projection (score).
  const int isv   = lane & 1;
  const int dbase = wc * 32 + ((lane & 15) >> 1);
  float sacc[4][4] = {};                  // [mi][r]
  #pragma unroll
  for(int mi = 0; mi < 4; ++mi){
    #pragma unroll
    for(int r = 0; r < 4; ++r){
      const int row = brow + wr*64 + mi*16 + (lane >> 4)*4 + r;  // global m
      #pragma unroll
      for(int ni = 0; ni < 4; ++ni){
        float sv = silu(acc[mi][ni][r]);
        int d = dbase + ni * 8;
        if(isv){
          vout[(row * H_ + h) * D_ + d] = f2bf(sv);
        } else {
          sacc[mi][r] += q[h * D_ + d] * sv;
        }
      }
    }
  }
  // reduce score partials across the 8 even lanes of each 16-lane group
  #pragma unroll
  for(int mi = 0; mi < 4; ++mi){
    #pragma unroll
    for(int r = 0; r < 4; ++r){
      float v = sacc[mi][r];
      v += __shfl_xor(v, 2);
      v += __shfl_xor(v, 4);
      v += __shfl_xor(v, 8);
      if((lane & 15) == 0)
        sl[wc][wr*64 + mi*16 + (lane >> 4)*4 + r] = v;
    }
  }
  __syncthreads();
  if(t < 128)
    s[(brow + t) * H_ + h] = sl[0][t] + sl[1][t];
}

// ---- online-softmax chunked scan --------------------------------------
// state: (m, den, num[64]); combine is the flash-attention op.
__global__ __launch_bounds__(64) void scan1(
    const unsigned short* __restrict__ v, const float* __restrict__ s,
    float* __restrict__ snum, float* __restrict__ sden, float* __restrict__ smax)
{
  const int blk = blockIdx.x;
  const int c = blk & (CHUNKS-1), bh = blk / CHUNKS;
  const int b = bh >> 4, h = bh & 15, lane = threadIdx.x;
  float m = -3.0e38f, den = 0.f, num = 0.f;
  const int t0 = c * CLEN;
  for(int tt = 0; tt < CLEN; ++tt){
    int t = t0 + tt;
    float st = s[(b*T_ + t)*H_ + h];
    float vt = bf2f(v[((b*T_ + t)*H_ + h)*D_ + lane]);
    float cm = fmaxf(m, st);
    float e  = __expf(m - cm);
    float p  = __expf(st - cm);
    den = den * e + p;
    num = num * e + p * vt;
    m = cm;
  }
  snum[blk*64 + lane] = num;
  if(lane == 0){ sden[blk] = den; smax[blk] = m; }
}

__global__ __launch_bounds__(64) void scan2(
    const unsigned short* __restrict__ v, const float* __restrict__ s,
    const float* __restrict__ snum, const float* __restrict__ sden,
    const float* __restrict__ smax, unsigned short* __restrict__ part)
{
  const int blk = blockIdx.x;
  const int c = blk & (CHUNKS-1), bh = blk / CHUNKS;
  const int b = bh >> 4, h = bh & 15, lane = threadIdx.x;
  float m = -3.0e38f, den = 0.f, num = 0.f;
  for(int cc = 0; cc < c; ++cc){           // prefix from chunk summaries
    int sb = bh*CHUNKS + cc;
    float m2 = smax[sb], d2 = sden[sb], n2 = snum[sb*64 + lane];
    float cm = fmaxf(m, m2);
    float e1 = __expf(m - cm), e2 = __expf(m2 - cm);
    den = den*e1 + d2*e2;
    num = num*e1 + n2*e2;
    m = cm;
  }
  const int t0 = c * CLEN;
  for(int tt = 0; tt < CLEN; ++tt){
    int t = t0 + tt;
    float st = s[(b*T_ + t)*H_ + h];
    float vt = bf2f(v[((b*T_ + t)*H_ + h)*D_ + lane]);
    float cm = fmaxf(m, st);
    float e  = __expf(m - cm);
    float p  = __expf(st - cm);
    den = den * e + p;
    num = num * e + p * vt;
    m = cm;
    part[(bh*T_ + t)*D_ + lane] = f2bf(num / den);
  }
}

// ---- K5: sum over heads ------------------------------------------------
__global__ __launch_bounds__(256) void reduceH(const unsigned short* __restrict__ part,
                                               float* __restrict__ out){
  int o = blockIdx.x * 256 + threadIdx.x;      // 2M outputs
  int d = o & 63, t = (o >> 6) & (T_ - 1), b = o >> 16;
  float acc = 0.f;
  #pragma unroll
  for(int h = 0; h < H_; ++h)
    acc += bf2f(part[((b*H_ + h)*T_ + t)*D_ + d]);
  out[o] = acc;
}

extern "C" void kernel_launch(void* const* d_in, const int* in_sizes, int n_in,
                              void* d_out, int out_size, void* d_ws, size_t ws_size,
                              hipStream_t stream){
  (void)in_sizes; (void)n_in; (void)out_size; (void)ws_size;
  const float* x = (const float*)d_in[0];
  const float* w = (const float*)d_in[1];
  const float* q = (const float*)d_in[2];
  float* out = (float*)d_out;
  char* ws = (char*)d_ws;

  // ws layout (bytes):
  //  [0,4M)      Wt  bf16 [N][K]
  //  [4M,68M)    xb  bf16 [M][K]   (aliased by `part` after GEMM is done)
  //  [68M,132M)  v   bf16 [M][H][D]
  //  [132M,134M) s   f32  [M][H]
  //  [134M,136M) snum f32 [B*H*CHUNKS][64]
  //  [136M,+32K) sden, [+32K,+64K) smax
  unsigned short* wt   = (unsigned short*)(ws);
  unsigned short* xb   = (unsigned short*)(ws + (4u  << 20));
  unsigned short* part = xb;
  unsigned short* vbuf = (unsigned short*)(ws + (68u << 20));
  float* s    = (float*)(ws + (132u << 20));
  float* snum = (float*)(ws + (134u << 20));
  float* sden = (float*)(ws + (136u << 20));
  float* smax = (float*)(ws + (136u << 20) + (1u << 15));

  cvt_x<<<2048, 256, 0, stream>>>(x, xb, M_ * K_);
  cvt_w<<<dim3(K_/64, N_/64), 256, 0, stream>>>(w, wt);
  gemm_fused<<<dim3(M_/BM, N_/BN), 256, 0, stream>>>(xb, wt, q, vbuf, s);
  scan1<<<B_*H_*CHUNKS, 64, 0, stream>>>(vbuf, s, snum, sden, smax);
  scan2<<<B_*H_*CHUNKS, 64, 0, stream>>>(vbuf, s, snum, sden, smax, part);
  reduceH<<<(M_*D_)/256, 256, 0, stream>>>(part, out);
}

// Round 2
// 300.905 us; speedup vs baseline: 1.1403x; 1.1403x over previous
//
#include <hip/hip_runtime.h>
#include <hip/hip_bf16.h>

#define B_ 32
#define T_ 1024
#define H_ 16
#define D_ 64
#define M_ (B_*T_)      // 32768 rows
#define N_ (H_*D_*2)    // 2048 cols (h,d,k)
#define K_ 1024
#define CHUNKS 16
#define CLEN (T_/CHUNKS)

typedef __bf16 bf16x8 __attribute__((ext_vector_type(8)));
typedef float  f32x4  __attribute__((ext_vector_type(4)));

__device__ __forceinline__ float bf2f(unsigned short u){
  union{ float f; unsigned int i; } c; c.i = ((unsigned int)u) << 16; return c.f;
}
__device__ __forceinline__ unsigned short f2bf(float f){
  union{ float f; unsigned int i; } c; c.f = f;
  unsigned int r = (c.i + 0x7FFFu + ((c.i >> 16) & 1u)) >> 16;   // RNE
  return (unsigned short)r;
}
__device__ __forceinline__ float silu(float x){ return x / (1.0f + __expf(-x)); }

__device__ __forceinline__ void gload16(const void* g, void* l){
  __builtin_amdgcn_global_load_lds(
      (const __attribute__((address_space(1))) void*)g,
      (__attribute__((address_space(3))) void*)l, 16, 0, 0);
}

#define BAR()   __builtin_amdgcn_s_barrier()
#define LGKM0() asm volatile("s_waitcnt lgkmcnt(0)" ::: "memory")
#define VM4()   asm volatile("s_waitcnt vmcnt(4)" ::: "memory")

// ---- K0: x f32 -> bf16 ------------------------------------------------
__global__ __launch_bounds__(256) void cvt_x(const float* __restrict__ x,
                                             unsigned short* __restrict__ xb, int n){
  int i = (blockIdx.x * 256 + threadIdx.x) * 4;
  int stride = gridDim.x * 256 * 4;
  for(; i < n; i += stride){
    float4 v = *(const float4*)(x + i);
    ushort4 o;
    o.x = f2bf(v.x); o.y = f2bf(v.y); o.z = f2bf(v.z); o.w = f2bf(v.w);
    *(ushort4*)(xb + i) = o;
  }
}

// ---- K1: W [K][N] f32 -> Wt [N][K] bf16 (LDS transpose) ---------------
__global__ __launch_bounds__(256) void cvt_w(const float* __restrict__ w,
                                             unsigned short* __restrict__ wt){
  __shared__ unsigned short tile[64][65];
  int kt = blockIdx.x * 64, nt = blockIdx.y * 64;
  int t = threadIdx.x, tn = t & 63, tk4 = t >> 6;
  #pragma unroll
  for(int r = 0; r < 16; ++r){
    int kl = r * 4 + tk4;
    tile[tn][kl] = f2bf(w[(kt + kl) * N_ + nt + tn]);
  }
  __syncthreads();
  #pragma unroll
  for(int r = 0; r < 16; ++r){
    int nl = r * 4 + tk4;
    wt[(nt + nl) * K_ + kt + tn] = tile[nl][tn];
  }
}

// ---- K2: 256x256 8-phase GEMM (bf16 MFMA) + silu + v-store + s = q.k ---
// LDS: 2 bufs x (A 256x64 + B 256x64) bf16 = 128 KiB, halves of 128x64 (16KB).
// Swizzle: physical 16B-slot s of row r holds logical kslot (s ^ (r&7)).
__global__ __launch_bounds__(512, 2) void gemm8(
    const unsigned short* __restrict__ xb,   // [M][K]
    const unsigned short* __restrict__ wt,   // [N][K]
    const float*  __restrict__ q,            // [H][D]
    unsigned short* __restrict__ vout,       // [M][H][D]
    float* __restrict__ s)                   // [M][H]
{
  __shared__ __align__(16) char lds[131072];
  __shared__ float sl[2][2][256];

  const int t = threadIdx.x, lane = t & 63, wid = t >> 6;
  const int wr = wid >> 2, wc = wid & 3;          // 2M x 4N waves
  const int l15 = lane & 15, l4 = lane >> 4;

  // bijective XCD swizzle: nwg=1024, by' = id&7 (one B-panel per XCD)
  const int id  = blockIdx.y * gridDim.x + blockIdx.x;
  const int swz = (id & 7) * 128 + (id >> 3);
  const int bx = swz & 127, by = swz >> 7;
  const int brow = bx * 256, bcol = by * 256;

  f32x4 acc[8][4] = {};
  bf16x8 af[8], b0[4], b1[4];

  // per-lane swizzled ds_read offsets (row&7 == l15&7 since mi*16 ≡ 0 mod 8)
  const int swl   = l15 & 7;
  const int aoff0 = l15 * 128 + (((0 + l4) ^ swl) << 4);   // kq=0
  const int aoff1 = l15 * 128 + (((4 + l4) ^ swl) << 4);   // kq=1

  auto stage = [&](int buf, int op, int half, const unsigned short* src,
                   int rowbase, int kt){
    char* base = lds + buf * 65536 + op * 32768 + half * 16384;
    #pragma unroll
    for(int L = 0; L < 2; ++L){
      int idx = L * 512 + t;
      int r = idx >> 3, ss = idx & 7;
      gload16(src + (size_t)(rowbase + half * 128 + r) * K_
                  + kt * 64 + ((ss ^ (r & 7)) << 3),
              base + idx * 16);
    }
  };
  auto rdA = [&](int buf, int miBase){
    const char* base = lds + buf * 65536 + wr * 16384;
    #pragma unroll
    for(int m = 0; m < 4; ++m){
      af[m*2+0] = *(const bf16x8*)(base + (miBase + m) * 2048 + aoff0);
      af[m*2+1] = *(const bf16x8*)(base + (miBase + m) * 2048 + aoff1);
    }
  };
  auto rdB = [&](int buf, int niBase, bf16x8 (&dst)[4]){
    const char* base = lds + buf * 65536 + 32768 + (wc >> 1) * 16384 + (wc & 1) * 8192;
    #pragma unroll
    for(int n = 0; n < 2; ++n){
      dst[n*2+0] = *(const bf16x8*)(base + (niBase + n) * 2048 + aoff0);
      dst[n*2+1] = *(const bf16x8*)(base + (niBase + n) * 2048 + aoff1);
    }
  };
  auto mmaq = [&](int miBase, bf16x8 (&bb)[4], int niBase){
    __builtin_amdgcn_s_setprio(1);
    #pragma unroll
    for(int m = 0; m < 4; ++m)
      #pragma unroll
      for(int n = 0; n < 2; ++n)
        #pragma unroll
        for(int k = 0; k < 2; ++k)
          acc[miBase+m][niBase+n] = __builtin_amdgcn_mfma_f32_16x16x32_bf16(
              af[m*2+k], bb[n*2+k], acc[miBase+m][niBase+n], 0, 0, 0);
    __builtin_amdgcn_s_setprio(0);
  };

  // prologue: buf0 <- tile0 (A+B), buf1 <- tile1 (B only; A staged in p1/p2)
  stage(0,0,0, xb, brow, 0); stage(0,0,1, xb, brow, 0);
  stage(0,1,0, wt, bcol, 0); stage(0,1,1, wt, bcol, 0);
  stage(1,1,0, wt, bcol, 1); stage(1,1,1, wt, bcol, 1);
  VM4(); BAR();

  // 16 K-tiles of 64, two per iteration, 8 phases per iteration
  for(int i = 0; i < 8; ++i){
    const int t1 = 2*i + 1;
    const int t2 = (2*i + 2) & 15;   // wraps harmlessly on last iter
    const int t3 = (2*i + 3) & 15;
    // p1: compute buf0 Q(m0-3, n0-1)
    rdA(0,0); rdB(0,0,b0); stage(1,0,0, xb, brow, t1);
    BAR(); LGKM0(); mmaq(0,b0,0); BAR();
    // p2: Q(m0-3, n2-3)
    rdB(0,2,b1); stage(1,0,1, xb, brow, t1);
    BAR(); LGKM0(); mmaq(0,b1,2); BAR();
    // p3: Q(m4-7, n2-3)
    rdA(0,4); stage(0,1,0, wt, bcol, t2);
    BAR(); LGKM0(); mmaq(4,b1,2); BAR();
    // p4: Q(m4-7, n0-1); counted vmcnt gate for buf1
    stage(0,1,1, wt, bcol, t2); VM4();
    BAR(); mmaq(4,b0,0); BAR();
    // p5..p8: same on buf1
    rdA(1,0); rdB(1,0,b0); stage(0,0,0, xb, brow, t2);
    BAR(); LGKM0(); mmaq(0,b0,0); BAR();
    rdB(1,2,b1); stage(0,0,1, xb, brow, t2);
    BAR(); LGKM0(); mmaq(0,b1,2); BAR();
    rdA(1,4); stage(1,1,0, wt, bcol, t3);
    BAR(); LGKM0(); mmaq(4,b1,2); BAR();
    stage(1,1,1, wt, bcol, t3); VM4();
    BAR(); mmaq(4,b0,0); BAR();
  }

  __syncthreads();   // drain everything before epilogue

  // Epilogue: rows gm = brow + wr*128 + mi*16 + l4*4 + r
  //           cols gcl = wc*64 + ni*16 + l15 (within 256-tile); head = by*2+(wc>>1)
  const int hh = by * 2 + (wc >> 1);
  float qv[4];
  #pragma unroll
  for(int ni = 0; ni < 4; ++ni){
    int gcl = wc*64 + ni*16 + l15;
    qv[ni] = q[hh * D_ + ((gcl & 127) >> 1)];
  }
  float sacc[8][4] = {};
  #pragma unroll
  for(int mi = 0; mi < 8; ++mi){
    #pragma unroll
    for(int r = 0; r < 4; ++r){
      const int gm = brow + wr*128 + mi*16 + l4*4 + r;
      #pragma unroll
      for(int ni = 0; ni < 4; ++ni){
        float sv = silu(acc[mi][ni][r]);
        int gcl = wc*64 + ni*16 + l15;
        int d   = (gcl & 127) >> 1;
        if(gcl & 1) vout[((size_t)gm * H_ + hh) * D_ + d] = f2bf(sv);
        else        sacc[mi][r] += qv[ni] * sv;
      }
    }
  }
  #pragma unroll
  for(int mi = 0; mi < 8; ++mi){
    #pragma unroll
    for(int r = 0; r < 4; ++r){
      float v = sacc[mi][r];
      v += __shfl_xor(v, 2); v += __shfl_xor(v, 4); v += __shfl_xor(v, 8);
      if(l15 == 0) sl[wc >> 1][wc & 1][wr*128 + mi*16 + l4*4 + r] = v;
    }
  }
  __syncthreads();
  {
    int hl = t >> 8, row = t & 255;
    s[(size_t)(brow + row) * H_ + by*2 + hl] = sl[hl][0][row] + sl[hl][1][row];
  }
}

// ---- online-softmax chunked scan --------------------------------------
__global__ __launch_bounds__(64) void scan1(
    const unsigned short* __restrict__ v, const float* __restrict__ s,
    float* __restrict__ snum, float* __restrict__ sden, float* __restrict__ smax)
{
  const int blk = blockIdx.x;
  const int c = blk & (CHUNKS-1), bh = blk / CHUNKS;
  const int b = bh >> 4, h = bh & 15, lane = threadIdx.x;
  float m = -3.0e38f, den = 0.f, num = 0.f;
  const int t0 = c * CLEN;
  for(int tt = 0; tt < CLEN; ++tt){
    int t = t0 + tt;
    float st = s[(b*T_ + t)*H_ + h];
    float vt = bf2f(v[((b*T_ + t)*H_ + h)*D_ + lane]);
    float cm = fmaxf(m, st);
    float e  = __expf(m - cm);
    float p  = __expf(st - cm);
    den = den * e + p;
    num = num * e + p * vt;
    m = cm;
  }
  snum[blk*64 + lane] = num;
  if(lane == 0){ sden[blk] = den; smax[blk] = m; }
}

__global__ __launch_bounds__(64) void scan2(
    const unsigned short* __restrict__ v, const float* __restrict__ s,
    const float* __restrict__ snum, const float* __restrict__ sden,
    const float* __restrict__ smax, unsigned short* __restrict__ part)
{
  const int blk = blockIdx.x;
  const int c = blk & (CHUNKS-1), bh = blk / CHUNKS;
  const int b = bh >> 4, h = bh & 15, lane = threadIdx.x;
  float m = -3.0e38f, den = 0.f, num = 0.f;
  for(int cc = 0; cc < c; ++cc){
    int sb = bh*CHUNKS + cc;
    float m2 = smax[sb], d2 = sden[sb], n2 = snum[sb*64 + lane];
    float cm = fmaxf(m, m2);
    float e1 = __expf(m - cm), e2 = __expf(m2 - cm);
    den = den*e1 + d2*e2;
    num = num*e1 + n2*e2;
    m = cm;
  }
  const int t0 = c * CLEN;
  for(int tt = 0; tt < CLEN; ++tt){
    int t = t0 + tt;
    float st = s[(b*T_ + t)*H_ + h];
    float vt = bf2f(v[((b*T_ + t)*H_ + h)*D_ + lane]);
    float cm = fmaxf(m, st);
    float e  = __expf(m - cm);
    float p  = __expf(st - cm);
    den = den * e + p;
    num = num * e + p * vt;
    m = cm;
    part[(bh*T_ + t)*D_ + lane] = f2bf(num / den);
  }
}

// ---- K5: sum over heads ------------------------------------------------
__global__ __launch_bounds__(256) void reduceH(const unsigned short* __restrict__ part,
                                               float* __restrict__ out){
  int o = blockIdx.x * 256 + threadIdx.x;
  int d = o & 63, t = (o >> 6) & (T_ - 1), b = o >> 16;
  float acc = 0.f;
  #pragma unroll
  for(int h = 0; h < H_; ++h)
    acc += bf2f(part[((b*H_ + h)*T_ + t)*D_ + d]);
  out[o] = acc;
}

extern "C" void kernel_launch(void* const* d_in, const int* in_sizes, int n_in,
                              void* d_out, int out_size, void* d_ws, size_t ws_size,
                              hipStream_t stream){
  (void)in_sizes; (void)n_in; (void)out_size; (void)ws_size;
  const float* x = (const float*)d_in[0];
  const float* w = (const float*)d_in[1];
  const float* q = (const float*)d_in[2];
  float* out = (float*)d_out;
  char* ws = (char*)d_ws;

  unsigned short* wt   = (unsigned short*)(ws);
  unsigned short* xb   = (unsigned short*)(ws + (4u  << 20));
  unsigned short* part = xb;
  unsigned short* vbuf = (unsigned short*)(ws + (68u << 20));
  float* s    = (float*)(ws + (132u << 20));
  float* snum = (float*)(ws + (134u << 20));
  float* sden = (float*)(ws + (136u << 20));
  float* smax = (float*)(ws + (136u << 20) + (1u << 15));

  cvt_x<<<2048, 256, 0, stream>>>(x, xb, M_ * K_);
  cvt_w<<<dim3(K_/64, N_/64), 256, 0, stream>>>(w, wt);
  gemm8<<<dim3(M_/256, N_/256), 512, 0, stream>>>(xb, wt, q, vbuf, s);
  scan1<<<B_*H_*CHUNKS, 64, 0, stream>>>(vbuf, s, snum, sden, smax);
  scan2<<<B_*H_*CHUNKS, 64, 0, stream>>>(vbuf, s, snum, sden, smax, part);
  reduceH<<<(M_*D_)/256, 256, 0, stream>>>(part, out);
}

// Round 3
// 252.998 us; speedup vs baseline: 1.3563x; 1.1894x over previous
//
#include <hip/hip_runtime.h>
#include <hip/hip_bf16.h>

#define B_ 32
#define T_ 1024
#define H_ 16
#define D_ 64
#define M_ (B_*T_)      // 32768 rows
#define N_ (H_*D_*2)    // 2048 cols
#define K_ 1024
#define CHUNKS 16
#define CLEN (T_/CHUNKS)

typedef __bf16 bf16x8 __attribute__((ext_vector_type(8)));
typedef float  f32x4  __attribute__((ext_vector_type(4)));

__device__ __forceinline__ float bf2f(unsigned short u){
  union{ float f; unsigned int i; } c; c.i = ((unsigned int)u) << 16; return c.f;
}
__device__ __forceinline__ unsigned short f2bf(float f){
  union{ float f; unsigned int i; } c; c.f = f;
  unsigned int r = (c.i + 0x7FFFu + ((c.i >> 16) & 1u)) >> 16;   // RNE
  return (unsigned short)r;
}
__device__ __forceinline__ float silu(float x){ return x / (1.0f + __expf(-x)); }

__device__ __forceinline__ void gload16(const void* g, void* l){
  __builtin_amdgcn_global_load_lds(
      (const __attribute__((address_space(1))) void*)g,
      (__attribute__((address_space(3))) void*)l, 16, 0, 0);
}

#define BAR()   __builtin_amdgcn_s_barrier()
#define LGKM0() asm volatile("s_waitcnt lgkmcnt(0)" ::: "memory")
#define VM4()   asm volatile("s_waitcnt vmcnt(4)" ::: "memory")

// ---- K0: x f32 -> bf16 ------------------------------------------------
__global__ __launch_bounds__(256) void cvt_x(const float* __restrict__ x,
                                             unsigned short* __restrict__ xb, int n){
  int i = (blockIdx.x * 256 + threadIdx.x) * 4;
  int stride = gridDim.x * 256 * 4;
  for(; i < n; i += stride){
    float4 v = *(const float4*)(x + i);
    ushort4 o;
    o.x = f2bf(v.x); o.y = f2bf(v.y); o.z = f2bf(v.z); o.w = f2bf(v.w);
    *(ushort4*)(xb + i) = o;
  }
}

// ---- K1: W [K][N] f32 -> Wt [n'][K] bf16, n' = h*128 + j*64 + d --------
__global__ __launch_bounds__(256) void cvt_w(const float* __restrict__ w,
                                             unsigned short* __restrict__ wt){
  __shared__ unsigned short tile[64][65];
  int kt = blockIdx.x * 64, nt = blockIdx.y * 64;
  int t = threadIdx.x, tn = t & 63, tk4 = t >> 6;
  #pragma unroll
  for(int r = 0; r < 16; ++r){
    int kl = r * 4 + tk4;
    tile[tn][kl] = f2bf(w[(kt + kl) * N_ + nt + tn]);
  }
  __syncthreads();
  #pragma unroll
  for(int r = 0; r < 16; ++r){
    int nl = r * 4 + tk4;
    int n  = nt + nl;
    int np = (n & ~127) | ((n & 1) << 6) | ((n >> 1) & 63);
    wt[(size_t)np * K_ + kt + tn] = tile[nl][tn];
  }
}

// ---- K2: 256x256 8-phase GEMM (bf16 MFMA) + silu + v-store + s = q.k ---
__global__ __launch_bounds__(512, 2) void gemm8(
    const unsigned short* __restrict__ xb,   // [M][K]
    const unsigned short* __restrict__ wt,   // [N'][K]
    const float*  __restrict__ q,            // [H][D]
    unsigned short* __restrict__ vout,       // [B][H][T][D]
    float* __restrict__ s)                   // [M][H]
{
  __shared__ __align__(16) char lds[131072];

  const int t = threadIdx.x, lane = t & 63, wid = t >> 6;
  const int wr = wid >> 2, wc = wid & 3;          // 2M x 4N waves
  const int l15 = lane & 15, l4 = lane >> 4;

  // bijective XCD swizzle: nwg=1024, by' = id&7
  const int id  = blockIdx.y * gridDim.x + blockIdx.x;
  const int swz = (id & 7) * 128 + (id >> 3);
  const int bx = swz & 127, by = swz >> 7;
  const int brow = bx * 256, bcol = by * 256;

  f32x4 acc[8][4] = {};
  bf16x8 af[8], b0[4], b1[4];

  const int swl   = l15 & 7;
  const int aoff0 = l15 * 128 + (((0 + l4) ^ swl) << 4);
  const int aoff1 = l15 * 128 + (((4 + l4) ^ swl) << 4);

  auto stage = [&](int buf, int op, int half, const unsigned short* src,
                   int rowbase, int kt){
    char* base = lds + buf * 65536 + op * 32768 + half * 16384;
    #pragma unroll
    for(int L = 0; L < 2; ++L){
      int idx = L * 512 + t;
      int r = idx >> 3, ss = idx & 7;
      gload16(src + (size_t)(rowbase + half * 128 + r) * K_
                  + kt * 64 + ((ss ^ (r & 7)) << 3),
              base + idx * 16);
    }
  };
  auto rdA = [&](int buf, int miBase){
    const char* base = lds + buf * 65536 + wr * 16384;
    #pragma unroll
    for(int m = 0; m < 4; ++m){
      af[m*2+0] = *(const bf16x8*)(base + (miBase + m) * 2048 + aoff0);
      af[m*2+1] = *(const bf16x8*)(base + (miBase + m) * 2048 + aoff1);
    }
  };
  auto rdB = [&](int buf, int niBase, bf16x8 (&dst)[4]){
    const char* base = lds + buf * 65536 + 32768 + (wc >> 1) * 16384 + (wc & 1) * 8192;
    #pragma unroll
    for(int n = 0; n < 2; ++n){
      dst[n*2+0] = *(const bf16x8*)(base + (niBase + n) * 2048 + aoff0);
      dst[n*2+1] = *(const bf16x8*)(base + (niBase + n) * 2048 + aoff1);
    }
  };
  auto mmaq = [&](int miBase, bf16x8 (&bb)[4], int niBase){
    __builtin_amdgcn_s_setprio(1);
    #pragma unroll
    for(int m = 0; m < 4; ++m)
      #pragma unroll
      for(int n = 0; n < 2; ++n)
        #pragma unroll
        for(int k = 0; k < 2; ++k)
          acc[miBase+m][niBase+n] = __builtin_amdgcn_mfma_f32_16x16x32_bf16(
              af[m*2+k], bb[n*2+k], acc[miBase+m][niBase+n], 0, 0, 0);
    __builtin_amdgcn_s_setprio(0);
  };

  stage(0,0,0, xb, brow, 0); stage(0,0,1, xb, brow, 0);
  stage(0,1,0, wt, bcol, 0); stage(0,1,1, wt, bcol, 0);
  stage(1,1,0, wt, bcol, 1); stage(1,1,1, wt, bcol, 1);
  VM4(); BAR();

  for(int i = 0; i < 8; ++i){
    const int t1 = 2*i + 1;
    const int t2 = (2*i + 2) & 15;
    const int t3 = (2*i + 3) & 15;
    rdA(0,0); rdB(0,0,b0); stage(1,0,0, xb, brow, t1);
    BAR(); LGKM0(); mmaq(0,b0,0); BAR();
    rdB(0,2,b1); stage(1,0,1, xb, brow, t1);
    BAR(); LGKM0(); mmaq(0,b1,2); BAR();
    rdA(0,4); stage(0,1,0, wt, bcol, t2);
    BAR(); LGKM0(); mmaq(4,b1,2); BAR();
    stage(0,1,1, wt, bcol, t2); VM4();
    BAR(); mmaq(4,b0,0); BAR();
    rdA(1,0); rdB(1,0,b0); stage(0,0,0, xb, brow, t2);
    BAR(); LGKM0(); mmaq(0,b0,0); BAR();
    rdB(1,2,b1); stage(0,0,1, xb, brow, t2);
    BAR(); LGKM0(); mmaq(0,b1,2); BAR();
    rdA(1,4); stage(1,1,0, wt, bcol, t3);
    BAR(); LGKM0(); mmaq(4,b1,2); BAR();
    stage(1,1,1, wt, bcol, t3); VM4();
    BAR(); mmaq(4,b0,0); BAR();
  }

  __syncthreads();

  // Epilogue. Columns of this wave: c = wc*64 + ni*16 + l15.
  // With split layout: head hh = by*2 + (wc>>1); wc even -> k (score), odd -> v.
  const int hh = by * 2 + (wc >> 1);
  if(wc & 1){
    #pragma unroll
    for(int mi = 0; mi < 8; ++mi)
      #pragma unroll
      for(int r = 0; r < 4; ++r){
        const int gm = brow + wr*128 + mi*16 + l4*4 + r;
        const int bb = gm >> 10, tt = gm & (T_-1);
        unsigned short* vrow = vout + (((size_t)bb*H_ + hh)*T_ + tt)*D_;
        #pragma unroll
        for(int ni = 0; ni < 4; ++ni)
          vrow[ni*16 + l15] = f2bf(silu(acc[mi][ni][r]));
      }
  } else {
    float qv[4];
    #pragma unroll
    for(int ni = 0; ni < 4; ++ni) qv[ni] = q[hh*D_ + ni*16 + l15];
    #pragma unroll
    for(int mi = 0; mi < 8; ++mi)
      #pragma unroll
      for(int r = 0; r < 4; ++r){
        float sc = 0.f;
        #pragma unroll
        for(int ni = 0; ni < 4; ++ni) sc += qv[ni] * silu(acc[mi][ni][r]);
        sc += __shfl_xor(sc, 1); sc += __shfl_xor(sc, 2);
        sc += __shfl_xor(sc, 4); sc += __shfl_xor(sc, 8);
        if(l15 == 0){
          const int gm = brow + wr*128 + mi*16 + l4*4 + r;
          s[(size_t)gm * H_ + hh] = sc;
        }
      }
  }
}

// ---- K3: chunk summaries (per b,h,chunk) -------------------------------
__global__ __launch_bounds__(64) void scan1(
    const unsigned short* __restrict__ v, const float* __restrict__ s,
    float* __restrict__ snum, float* __restrict__ sden, float* __restrict__ smax)
{
  const int blk = blockIdx.x;
  const int c = blk & (CHUNKS-1), bh = blk / CHUNKS;
  const int b = bh >> 4, h = bh & 15, lane = threadIdx.x;
  float m = -3.0e38f, den = 0.f, num = 0.f;
  const unsigned short* vb = v + (((size_t)b*H_ + h)*T_ + c*CLEN)*D_;
  const float* sb = s + ((size_t)b*T_ + c*CLEN)*H_ + h;
  for(int tt = 0; tt < CLEN; ++tt){
    float st = sb[tt*H_];
    float vt = bf2f(vb[tt*D_ + lane]);
    float cm = fmaxf(m, st);
    float e  = __expf(m - cm);
    float p  = __expf(st - cm);
    den = den * e + p;
    num = num * e + p * vt;
    m = cm;
  }
  snum[blk*64 + lane] = num;
  if(lane == 0){ sden[blk] = den; smax[blk] = m; }
}

// ---- K4: fused per-chunk scan over all 16 heads + head-sum -> out ------
__global__ __launch_bounds__(256) void scan2h(
    const unsigned short* __restrict__ v, const float* __restrict__ s,
    const float* __restrict__ snum, const float* __restrict__ sden,
    const float* __restrict__ smax, float* __restrict__ out)
{
  __shared__ float sst[CLEN*H_];        // 4 KB
  __shared__ float oacc[4][CLEN][D_];   // 64 KB
  const int blk = blockIdx.x;
  const int c = blk & (CHUNKS-1), b = blk >> 4;
  const int t = threadIdx.x, lane = t & 63, w = t >> 6;

  const float* sbase = s + ((size_t)b*T_ + c*CLEN) * H_;
  for(int i = t; i < CLEN*H_; i += 256) sst[i] = sbase[i];
  __syncthreads();

  const int h0 = w * 4;
  float num[4], den[4], m[4];
  #pragma unroll
  for(int j = 0; j < 4; ++j){ num[j] = 0.f; den[j] = 0.f; m[j] = -3.0e38f; }

  for(int cc = 0; cc < c; ++cc){
    #pragma unroll
    for(int j = 0; j < 4; ++j){
      int sb = (b*H_ + h0 + j)*CHUNKS + cc;
      float m2 = smax[sb], d2 = sden[sb], n2 = snum[sb*64 + lane];
      float cm = fmaxf(m[j], m2);
      float e1 = __expf(m[j]-cm), e2 = __expf(m2-cm);
      den[j] = den[j]*e1 + d2*e2;
      num[j] = num[j]*e1 + n2*e2;
      m[j] = cm;
    }
  }

  const unsigned short* vb = v + (((size_t)b*H_ + h0)*T_ + c*CLEN)*D_;
  for(int tt = 0; tt < CLEN; ++tt){
    float o = 0.f;
    #pragma unroll
    for(int j = 0; j < 4; ++j){
      float st = sst[tt*H_ + h0 + j];
      float vt = bf2f(vb[(size_t)j*T_*D_ + tt*D_ + lane]);
      float cm = fmaxf(m[j], st);
      float e = __expf(m[j]-cm), p = __expf(st-cm);
      den[j] = den[j]*e + p;
      num[j] = num[j]*e + p*vt;
      m[j] = cm;
      o += num[j] / den[j];
    }
    oacc[w][tt][lane] = o;
  }
  __syncthreads();

  {
    int tt = t >> 2, db = (t & 3) * 16;
    float* ob = out + ((size_t)b*T_ + c*CLEN + tt) * D_ + db;
    #pragma unroll
    for(int qd = 0; qd < 4; ++qd){
      f32x4 a0 = *(const f32x4*)&oacc[0][tt][db + qd*4];
      f32x4 a1 = *(const f32x4*)&oacc[1][tt][db + qd*4];
      f32x4 a2 = *(const f32x4*)&oacc[2][tt][db + qd*4];
      f32x4 a3 = *(const f32x4*)&oacc[3][tt][db + qd*4];
      f32x4 r = (a0 + a1) + (a2 + a3);
      *(f32x4*)(ob + qd*4) = r;
    }
  }
}

extern "C" void kernel_launch(void* const* d_in, const int* in_sizes, int n_in,
                              void* d_out, int out_size, void* d_ws, size_t ws_size,
                              hipStream_t stream){
  (void)in_sizes; (void)n_in; (void)out_size; (void)ws_size;
  const float* x = (const float*)d_in[0];
  const float* w = (const float*)d_in[1];
  const float* q = (const float*)d_in[2];
  float* out = (float*)d_out;
  char* ws = (char*)d_ws;

  unsigned short* wt   = (unsigned short*)(ws);
  unsigned short* xb   = (unsigned short*)(ws + (4u  << 20));
  unsigned short* vbuf = (unsigned short*)(ws + (68u << 20));
  float* s    = (float*)(ws + (132u << 20));
  float* snum = (float*)(ws + (134u << 20));
  float* sden = (float*)(ws + (136u << 20));
  float* smax = (float*)(ws + (136u << 20) + (1u << 15));

  cvt_x<<<2048, 256, 0, stream>>>(x, xb, M_ * K_);
  cvt_w<<<dim3(K_/64, N_/64), 256, 0, stream>>>(w, wt);
  gemm8<<<dim3(M_/256, N_/256), 512, 0, stream>>>(xb, wt, q, vbuf, s);
  scan1<<<B_*H_*CHUNKS, 64, 0, stream>>>(vbuf, s, snum, sden, smax);
  scan2h<<<B_*CHUNKS, 256, 0, stream>>>(vbuf, s, snum, sden, smax, out);
}